// Round 5
// baseline (374.991 us; speedup 1.0000x reference)
//
#include <hip/hip_runtime.h>
#include <hip/hip_bf16.h>
#include <stdint.h>

#define NCLS 36
#define HDIM 256
#define BSZ  32
#define LLOC 196
#define DIN  1024
#define NCH  9216          // NCLS*HDIM

#define XG_N 294912        // BSZ*NCH
#define AT_N 225792        // BSZ*NCLS*LLOC
#define V_N  1179648       // BSZ*NCLS*DIN

// ---------------------------------------------------------------------------
// kA: xg[b][n] = bg[n] + sum_k gap[b][k]*Wg[k][n].  Full K per block:
// 4 waves each take a 256-k quarter, 64 n lanes, 16 b accumulators;
// cross-wave reduce through LDS. grid (144 nt64, 2 bh16) = 288 blocks.
__global__ __launch_bounds__(256) void kA_xg(
    const float* __restrict__ Wg, const float* __restrict__ gap,
    const float* __restrict__ bg, float* __restrict__ xg) {
  __shared__ float red[4][16][64];
  const int tid  = threadIdx.x;
  const int w    = __builtin_amdgcn_readfirstlane(tid >> 6);   // k-quarter
  const int lane = tid & 63;
  const int n0   = blockIdx.x * 64;
  const int b0   = blockIdx.y * 16;
  const int k0   = w * 256;

  float acc[16] = {0,0,0,0,0,0,0,0,0,0,0,0,0,0,0,0};
  const float* wp = Wg + (size_t)k0 * NCH + n0 + lane;
  const float* gp = gap + (size_t)b0 * DIN + k0;
  for (int k4 = 0; k4 < 64; ++k4) {
    float w0 = wp[(size_t)(k4 * 4 + 0) * NCH];
    float w1 = wp[(size_t)(k4 * 4 + 1) * NCH];
    float w2 = wp[(size_t)(k4 * 4 + 2) * NCH];
    float w3 = wp[(size_t)(k4 * 4 + 3) * NCH];
    #pragma unroll
    for (int bi = 0; bi < 16; ++bi) {
      float4 g = *(const float4*)&gp[(size_t)bi * DIN + k4 * 4];  // s_load
      acc[bi] += g.x * w0 + g.y * w1 + g.z * w2 + g.w * w3;
    }
  }
  #pragma unroll
  for (int bi = 0; bi < 16; ++bi) red[w][bi][lane] = acc[bi];
  __syncthreads();
  const int n = tid & 63;
  #pragma unroll
  for (int bb = 0; bb < 4; ++bb) {
    int b = (tid >> 6) * 4 + bb;
    float s = red[0][b][n] + red[1][b][n] + red[2][b][n] + red[3][b][n]
            + bg[n0 + n];
    xg[(size_t)(b0 + b) * NCH + n0 + n] = s;
  }
}

// ---------------------------------------------------------------------------
// kC: V[b][c][k] = sum_h Wl[k][c*256+h] * xg[b][c*256+h]
// grid (36 c, 8 kc128) = 288 blocks. Wl streamed exactly once. 256 threads =
// 128 k x 2 b-halves (16 b accumulators each). xg via scalar loads.
__global__ __launch_bounds__(256) void kC_V(
    const float* __restrict__ Wl, const float* __restrict__ xg,
    float* __restrict__ V) {
  const int c  = blockIdx.x;
  const int k  = blockIdx.y * 128 + (threadIdx.x & 127);
  const int b0 = __builtin_amdgcn_readfirstlane(threadIdx.x >> 7) * 16;
  float acc[16] = {0,0,0,0,0,0,0,0,0,0,0,0,0,0,0,0};
  const float* wl = Wl + (size_t)k * NCH + c * HDIM;
  const float* xp = xg + (size_t)b0 * NCH + c * HDIM;
  for (int j = 0; j < 64; ++j) {
    float4 w = *(const float4*)&wl[j * 4];
    #pragma unroll
    for (int bi = 0; bi < 16; ++bi) {
      float4 x = *(const float4*)&xp[(size_t)bi * NCH + j * 4];   // s_load
      acc[bi] += w.x * x.x + w.y * x.y + w.z * x.z + w.w * x.w;
    }
  }
  #pragma unroll
  for (int bi = 0; bi < 16; ++bi)
    V[(size_t)((b0 + bi) * NCLS + c) * DIN + k] = acc[bi];
}

// ---------------------------------------------------------------------------
// kDE: scores + softmax fused. grid (32 b, 6 cg6) = 192 blocks.
// thread = l (196 active), 6 classes per block; V via scalar loads;
// in-block softmax; writes attn2[b][c][l].
__global__ __launch_bounds__(256) void kDE_attn(
    const float* __restrict__ local, const float* __restrict__ V,
    float* __restrict__ attn2) {
  __shared__ float sc_s[6][256];
  const int b  = blockIdx.x;
  const int c0 = blockIdx.y * 6;
  const int l  = threadIdx.x;

  if (l < LLOC) {
    const float* lp = local + (size_t)(b * LLOC + l) * DIN;
    const float* vp = V + (size_t)(b * NCLS + c0) * DIN;
    float acc[6] = {0,0,0,0,0,0};
    for (int j = 0; j < 256; ++j) {
      float4 a = *(const float4*)&lp[j * 4];
      #pragma unroll
      for (int ci = 0; ci < 6; ++ci) {
        float4 v = *(const float4*)&vp[(size_t)ci * DIN + j * 4];  // s_load
        acc[ci] += a.x * v.x + a.y * v.y + a.z * v.z + a.w * v.w;
      }
    }
    #pragma unroll
    for (int ci = 0; ci < 6; ++ci) sc_s[ci][l] = acc[ci];
  }
  __syncthreads();

  const int w = threadIdx.x >> 6, lane = threadIdx.x & 63;
  for (int ci = w; ci < 6; ci += 4) {
    float m = -1e30f;
    for (int l2 = lane; l2 < LLOC; l2 += 64) m = fmaxf(m, sc_s[ci][l2]);
    #pragma unroll
    for (int off = 32; off >= 1; off >>= 1) m = fmaxf(m, __shfl_xor(m, off));
    float e[4]; int nl = 0; float sum = 0.f;
    for (int l2 = lane; l2 < LLOC; l2 += 64) {
      e[nl] = __expf(sc_s[ci][l2] - m); sum += e[nl]; ++nl;
    }
    #pragma unroll
    for (int off = 32; off >= 1; off >>= 1) sum += __shfl_xor(sum, off);
    float inv = 1.0f / sum;
    nl = 0;
    for (int l2 = lane; l2 < LLOC; l2 += 64)
      attn2[(size_t)(b * NCLS + c0 + ci) * LLOC + l2] = e[nl++] * inv;
  }
}

// ---------------------------------------------------------------------------
// kF: U[b][c][k] = sum_l attn2[b][c][l] * local[b][l][k]
// grid (32 b, 8 ks128) = 256 blocks. local streamed exactly once.
// 256 threads = 128 k x 2 c-halves (18 classes each). attn2 via scalar loads.
__global__ __launch_bounds__(256) void kF_U(
    const float* __restrict__ local, const float* __restrict__ attn2,
    float* __restrict__ U) {
  const int b  = blockIdx.x;
  const int k  = blockIdx.y * 128 + (threadIdx.x & 127);
  const int c0 = __builtin_amdgcn_readfirstlane(threadIdx.x >> 7) * 18;
  float acc[18];
  #pragma unroll
  for (int ci = 0; ci < 18; ++ci) acc[ci] = 0.f;
  const float* lp = local + (size_t)b * LLOC * DIN + k;
  const float* ap = attn2 + (size_t)(b * NCLS + c0) * LLOC;
  for (int l4 = 0; l4 < 49; ++l4) {
    float a0 = lp[(size_t)(l4 * 4 + 0) * DIN];
    float a1 = lp[(size_t)(l4 * 4 + 1) * DIN];
    float a2 = lp[(size_t)(l4 * 4 + 2) * DIN];
    float a3 = lp[(size_t)(l4 * 4 + 3) * DIN];
    #pragma unroll
    for (int ci = 0; ci < 18; ++ci) {
      float4 w = *(const float4*)&ap[(size_t)ci * LLOC + l4 * 4];  // s_load
      acc[ci] += a0 * w.x + a1 * w.y + a2 * w.z + a3 * w.w;
    }
  }
  #pragma unroll
  for (int ci = 0; ci < 18; ++ci)
    U[(size_t)(b * NCLS + c0 + ci) * DIN + k] = acc[ci];
}

// ---------------------------------------------------------------------------
// kG: wsh_part[ks][b][c][h] = sum_{k in chunk128} U[b][c][k] * Wl[k][c*256+h]
// grid (36 c, 8 ks) = 288 blocks. Wl streamed exactly once (all 32 b per
// block, two 16-accumulator banks). thread = h (coalesced Wl), U -> s_load.
__global__ __launch_bounds__(256) void kG_ws(
    const float* __restrict__ Wl, const float* __restrict__ U,
    float* __restrict__ wsh_part) {
  const int c  = blockIdx.x;
  const int kc = blockIdx.y * 128;
  const int h  = threadIdx.x;
  float acc0[16] = {0,0,0,0,0,0,0,0,0,0,0,0,0,0,0,0};
  float acc1[16] = {0,0,0,0,0,0,0,0,0,0,0,0,0,0,0,0};
  const float* wp = Wl + (size_t)kc * NCH + c * HDIM + h;
  const float* up = U + (size_t)c * DIN + kc;
  for (int k4 = 0; k4 < 32; ++k4) {
    float w0 = wp[(size_t)(k4 * 4 + 0) * NCH];
    float w1 = wp[(size_t)(k4 * 4 + 1) * NCH];
    float w2 = wp[(size_t)(k4 * 4 + 2) * NCH];
    float w3 = wp[(size_t)(k4 * 4 + 3) * NCH];
    #pragma unroll
    for (int bi = 0; bi < 16; ++bi) {
      float4 u = *(const float4*)&up[(size_t)bi * NCLS * DIN + k4 * 4];
      acc0[bi] += u.x * w0 + u.y * w1 + u.z * w2 + u.w * w3;
    }
    #pragma unroll
    for (int bi = 0; bi < 16; ++bi) {
      float4 u = *(const float4*)&up[(size_t)(bi + 16) * NCLS * DIN + k4 * 4];
      acc1[bi] += u.x * w0 + u.y * w1 + u.z * w2 + u.w * w3;
    }
  }
  const size_t base = (size_t)blockIdx.y * XG_N + c * HDIM + h;
  #pragma unroll
  for (int bi = 0; bi < 16; ++bi) {
    wsh_part[base + (size_t)bi * NCH]        = acc0[bi];
    wsh_part[base + (size_t)(bi + 16) * NCH] = acc1[bi];
  }
}

// ---------------------------------------------------------------------------
// kH: ws = sum8 wsh_part + bl; hid = relu(ws@Wh+bh); bbox/presence heads.
// grid (32 b, 12 cg3) x 256 (thread = j).
__global__ __launch_bounds__(256) void kH_heads(
    const float* __restrict__ Wh, const float* __restrict__ bh,
    const float* __restrict__ Wr, const float* __restrict__ br,
    const float* __restrict__ Wc, const float* __restrict__ bc,
    const float* __restrict__ bl,
    const float* __restrict__ wsh_part, float* __restrict__ out) {
  __shared__ float ws_s[3][HDIM];
  __shared__ float hid_s[3][HDIM];
  const int b = blockIdx.x, c0 = blockIdx.y * 3;
  const int j = threadIdx.x;

  #pragma unroll
  for (int ci = 0; ci < 3; ++ci) {
    size_t base = (size_t)b * NCH + (c0 + ci) * HDIM + j;
    float s = bl[(c0 + ci) * HDIM + j];
    #pragma unroll
    for (int p = 0; p < 8; ++p) s += wsh_part[(size_t)p * XG_N + base];
    ws_s[ci][j] = s;
  }
  __syncthreads();

  float acc[3] = {0,0,0};
  for (int h = 0; h < HDIM; ++h) {
    float whj = Wh[(size_t)h * HDIM + j];
    acc[0] += ws_s[0][h] * whj;
    acc[1] += ws_s[1][h] * whj;
    acc[2] += ws_s[2][h] * whj;
  }
  float bj = bh[j];
  #pragma unroll
  for (int ci = 0; ci < 3; ++ci) hid_s[ci][j] = fmaxf(acc[ci] + bj, 0.0f);
  __syncthreads();

  const int r = j >> 6, j0 = j & 63;
  for (int ci = 0; ci < 3; ++ci) {
    const int c = c0 + ci;
    float s = 0.f;
    #pragma unroll
    for (int m = 0; m < 4; ++m)
      s += hid_s[ci][j0 + 64 * m] * Wr[(j0 + 64 * m) * 4 + r];
    #pragma unroll
    for (int off = 32; off >= 1; off >>= 1) s += __shfl_xor(s, off);
    if (j0 == 0) out[(size_t)b * (NCLS * 4) + c * 4 + r] = s + br[r];
    if (r == 0) {
      float p = 0.f;
      #pragma unroll
      for (int m = 0; m < 4; ++m)
        p += hid_s[ci][j0 + 64 * m] * Wc[j0 + 64 * m];
      #pragma unroll
      for (int off = 32; off >= 1; off >>= 1) p += __shfl_xor(p, off);
      if (j0 == 0) out[BSZ * NCLS * 4 + b * NCLS + c] = p + bc[0];
    }
  }
}

// ---------------------------------------------------------------------------
extern "C" void kernel_launch(void* const* d_in, const int* in_sizes, int n_in,
                              void* d_out, int out_size, void* d_ws, size_t ws_size,
                              hipStream_t stream) {
  const float* local = (const float*)d_in[0];
  const float* gap   = (const float*)d_in[1];
  const float* Wl    = (const float*)d_in[2];
  const float* bl    = (const float*)d_in[3];
  const float* Wg    = (const float*)d_in[4];
  const float* bg    = (const float*)d_in[5];
  const float* Wh    = (const float*)d_in[6];
  const float* bh    = (const float*)d_in[7];
  const float* Wr    = (const float*)d_in[8];
  const float* br    = (const float*)d_in[9];
  const float* Wc    = (const float*)d_in[10];
  const float* bc    = (const float*)d_in[11];
  float* out         = (float*)d_out;

  float* xg    = (float*)d_ws;            // XG_N
  float* V     = xg + XG_N;               // V_N
  float* attn2 = V + V_N;                 // AT_N
  float* U     = attn2 + AT_N;            // V_N
  float* wshp  = U + V_N;                 // 8*XG_N
  // total ~21 MB

  kA_xg  <<<dim3(144, 2), dim3(256), 0, stream>>>(Wg, gap, bg, xg);
  kC_V   <<<dim3(36, 8),  dim3(256), 0, stream>>>(Wl, xg, V);
  kDE_attn<<<dim3(32, 6), dim3(256), 0, stream>>>(local, V, attn2);
  kF_U   <<<dim3(32, 8),  dim3(256), 0, stream>>>(local, attn2, U);
  kG_ws  <<<dim3(36, 8),  dim3(256), 0, stream>>>(Wl, U, wshp);
  kH_heads<<<dim3(32, 12), dim3(256), 0, stream>>>(Wh, bh, Wr, br, Wc, bc, bl, wshp, out);
}

// Round 6
// 268.749 us; speedup vs baseline: 1.3953x; 1.3953x over previous
//
#include <hip/hip_runtime.h>
#include <hip/hip_bf16.h>
#include <stdint.h>

#define NCLS 36
#define HDIM 256
#define BSZ  32
#define LLOC 196
#define DIN  1024
#define NCH  9216          // NCLS*HDIM

#define XG_N 294912        // BSZ*NCH
#define SC_N 225792        // BSZ*NCLS*LLOC
#define V_N  1179648       // BSZ*NCLS*DIN

// ---------------------------------------------------------------------------
// kB: xg_part[ks][b][n] = sum_{k chunk128} gap[b][k] * Wg[k][n]
// grid (36 nt256, 8 ks128, 2 bh16) = 576 blocks. thread = n (coalesced Wg).
// gap slice (16 b x 128 k = 8 KB) staged in LDS, broadcast ds_read in loop.
__global__ __launch_bounds__(256) void kB_xg_part(
    const float* __restrict__ Wg, const float* __restrict__ gap,
    float* __restrict__ xg_part) {
  __shared__ float4 gs[16][32];
  const int tid = threadIdx.x;
  const int n   = blockIdx.x * 256 + tid;
  const int kc  = blockIdx.y * 128;
  const int b0  = blockIdx.z * 16;

  for (int i = tid; i < 512; i += 256) {
    int bi = i >> 5, pos = i & 31;
    gs[bi][pos] = *(const float4*)&gap[(size_t)(b0 + bi) * DIN + kc + pos * 4];
  }
  __syncthreads();

  float acc[16] = {0,0,0,0,0,0,0,0,0,0,0,0,0,0,0,0};
  const float* wp = Wg + (size_t)kc * NCH + n;
  #pragma unroll 2
  for (int k4 = 0; k4 < 32; ++k4) {
    float w0 = wp[(size_t)(k4 * 4 + 0) * NCH];
    float w1 = wp[(size_t)(k4 * 4 + 1) * NCH];
    float w2 = wp[(size_t)(k4 * 4 + 2) * NCH];
    float w3 = wp[(size_t)(k4 * 4 + 3) * NCH];
    #pragma unroll
    for (int bi = 0; bi < 16; ++bi) {
      float4 g = gs[bi][k4];                       // LDS broadcast
      acc[bi] += g.x * w0 + g.y * w1 + g.z * w2 + g.w * w3;
    }
  }
  #pragma unroll
  for (int bi = 0; bi < 16; ++bi)
    xg_part[(size_t)blockIdx.y * XG_N + (size_t)(b0 + bi) * NCH + n] = acc[bi];
}

// kBr: xg = bg + sum of 8 partials. grid 1152 x 256.
__global__ void kBr_xg(const float* __restrict__ xg_part,
                       const float* __restrict__ bg, float* __restrict__ xg) {
  int i = blockIdx.x * 256 + threadIdx.x;
  float s = bg[i % NCH];
  #pragma unroll
  for (int p = 0; p < 8; ++p) s += xg_part[(size_t)p * XG_N + i];
  xg[i] = s;
}

// ---------------------------------------------------------------------------
// kC: V[b][c][k] = sum_h Wl[k][c*256+h] * xg[b][c*256+h]
// grid (36 c, 4 kc256, 4 bq8) = 576 blocks. thread = k (per-lane row walk,
// L1-amortized). xg slice (8 b x 256 h = 8 KB) staged in LDS.
__global__ __launch_bounds__(256) void kC_V(
    const float* __restrict__ Wl, const float* __restrict__ xg,
    float* __restrict__ V) {
  __shared__ float4 xs[8][64];
  const int tid = threadIdx.x;
  const int c   = blockIdx.x;
  const int k   = blockIdx.y * 256 + tid;
  const int b0  = blockIdx.z * 8;

  for (int i = tid; i < 512; i += 256) {
    int bi = i >> 6, j = i & 63;
    xs[bi][j] = *(const float4*)&xg[(size_t)(b0 + bi) * NCH + c * HDIM + j * 4];
  }
  __syncthreads();

  float acc[8] = {0,0,0,0,0,0,0,0};
  const float* wl = Wl + (size_t)k * NCH + c * HDIM;
  #pragma unroll 2
  for (int j = 0; j < 64; ++j) {
    float4 w = *(const float4*)&wl[j * 4];
    #pragma unroll
    for (int bi = 0; bi < 8; ++bi) {
      float4 x = xs[bi][j];                        // LDS broadcast
      acc[bi] += w.x * x.x + w.y * x.y + w.z * x.z + w.w * x.w;
    }
  }
  #pragma unroll
  for (int bi = 0; bi < 8; ++bi)
    V[(size_t)((b0 + bi) * NCLS + c) * DIN + k] = acc[bi];
}

// ---------------------------------------------------------------------------
// kD: sc_part[ks][b][c][l] = sum_{k chunk128} local[b][l][k] * V[b][c][k]
// grid (32 b, 3 cg12, 8 ks) = 768 blocks. thread = l (196 active).
// V slice (12 c x 128 k = 6 KB) staged in LDS.
__global__ __launch_bounds__(256) void kD_scores(
    const float* __restrict__ local, const float* __restrict__ V,
    float* __restrict__ sc_part) {
  __shared__ float4 vs[12][32];
  const int tid = threadIdx.x;
  const int b   = blockIdx.x;
  const int cg  = blockIdx.y;
  const int ks  = blockIdx.z;

  for (int i = tid; i < 384; i += 256) {
    int ci = i >> 5, pos = i & 31;
    vs[ci][pos] = *(const float4*)&V[(size_t)(b * NCLS + cg * 12 + ci) * DIN
                                     + ks * 128 + pos * 4];
  }
  __syncthreads();

  const int l = tid;
  if (l >= LLOC) return;
  const float* lp = local + (size_t)(b * LLOC + l) * DIN + ks * 128;
  float acc[12] = {0,0,0,0,0,0,0,0,0,0,0,0};
  #pragma unroll 2
  for (int j = 0; j < 32; ++j) {
    float4 a = *(const float4*)&lp[j * 4];
    #pragma unroll
    for (int ci = 0; ci < 12; ++ci) {
      float4 v = vs[ci][j];                        // LDS broadcast
      acc[ci] += a.x * v.x + a.y * v.y + a.z * v.z + a.w * v.w;
    }
  }
  #pragma unroll
  for (int ci = 0; ci < 12; ++ci)
    sc_part[(size_t)ks * SC_N + (size_t)(b * NCLS + cg * 12 + ci) * LLOC + l] = acc[ci];
}

// ---------------------------------------------------------------------------
// kE: sum 8 partials + softmax over l; write attn2[b][c][l]. grid (32,36) x 64.
__global__ __launch_bounds__(64) void kE_softmax(
    const float* __restrict__ sc_part, float* __restrict__ attn2) {
  const int b = blockIdx.x, c = blockIdx.y, t = threadIdx.x;
  const size_t base = (size_t)(b * NCLS + c) * LLOC;
  float sc[4];
  int nl = 0;
  float m = -1e30f;
  for (int l = t; l < LLOC; l += 64) {
    float s = 0.f;
    #pragma unroll
    for (int p = 0; p < 8; ++p) s += sc_part[(size_t)p * SC_N + base + l];
    sc[nl++] = s; m = fmaxf(m, s);
  }
  #pragma unroll
  for (int off = 32; off >= 1; off >>= 1) m = fmaxf(m, __shfl_xor(m, off));
  float sum = 0.f;
  for (int i = 0; i < nl; ++i) { sc[i] = __expf(sc[i] - m); sum += sc[i]; }
  #pragma unroll
  for (int off = 32; off >= 1; off >>= 1) sum += __shfl_xor(sum, off);
  float inv = 1.0f / sum;
  nl = 0;
  for (int l = t; l < LLOC; l += 64) attn2[base + l] = sc[nl++] * inv;
}

// ---------------------------------------------------------------------------
// kF: U[b][c][k] = sum_l attn2[b][c][l] * local[b][l][k]
// grid (32 b, 8 ks128, 3 cg12) = 768 blocks. 256 thr = 128 k x 2 c-halves
// (6 classes each). attn slice (12 x 196 = 9.2 KB) staged in LDS.
__global__ __launch_bounds__(256) void kF_U(
    const float* __restrict__ local, const float* __restrict__ attn2,
    float* __restrict__ U) {
  __shared__ float4 as4[12][49];
  const int tid  = threadIdx.x;
  const int b    = blockIdx.x;
  const int k    = blockIdx.y * 128 + (tid & 127);
  const int half = __builtin_amdgcn_readfirstlane(tid >> 7);   // wave-uniform
  const int cb   = blockIdx.z * 12;

  for (int i = tid; i < 588; i += 256) {
    int ci = i / 49, pos = i - ci * 49;
    as4[ci][pos] = *(const float4*)&attn2[(size_t)(b * NCLS + cb + ci) * LLOC + pos * 4];
  }
  __syncthreads();

  float acc[6] = {0,0,0,0,0,0};
  const float* lp = local + (size_t)b * LLOC * DIN + k;
  #pragma unroll 2
  for (int l4 = 0; l4 < 49; ++l4) {
    float a0 = lp[(size_t)(l4 * 4 + 0) * DIN];
    float a1 = lp[(size_t)(l4 * 4 + 1) * DIN];
    float a2 = lp[(size_t)(l4 * 4 + 2) * DIN];
    float a3 = lp[(size_t)(l4 * 4 + 3) * DIN];
    #pragma unroll
    for (int ci = 0; ci < 6; ++ci) {
      float4 w = as4[half * 6 + ci][l4];           // LDS broadcast
      acc[ci] += a0 * w.x + a1 * w.y + a2 * w.z + a3 * w.w;
    }
  }
  #pragma unroll
  for (int ci = 0; ci < 6; ++ci)
    U[(size_t)(b * NCLS + cb + half * 6 + ci) * DIN + k] = acc[ci];
}

// ---------------------------------------------------------------------------
// kG: wsh_part[ks][b][c][h] = sum_{k chunk128} U[b][c][k] * Wl[k][c*256+h]
// grid (36 c, 8 ks, 2 bh16) = 576 blocks. thread = h (coalesced Wl).
// U slice (16 b x 128 k = 8 KB) staged in LDS.
__global__ __launch_bounds__(256) void kG_ws(
    const float* __restrict__ Wl, const float* __restrict__ U,
    float* __restrict__ wsh_part) {
  __shared__ float4 us[16][32];
  const int tid = threadIdx.x;
  const int c   = blockIdx.x;
  const int kc  = blockIdx.y * 128;
  const int b0  = blockIdx.z * 16;
  const int h   = tid;

  for (int i = tid; i < 512; i += 256) {
    int bi = i >> 5, pos = i & 31;
    us[bi][pos] = *(const float4*)&U[(size_t)((b0 + bi) * NCLS + c) * DIN + kc + pos * 4];
  }
  __syncthreads();

  float acc[16] = {0,0,0,0,0,0,0,0,0,0,0,0,0,0,0,0};
  const float* wp = Wl + (size_t)kc * NCH + c * HDIM + h;
  #pragma unroll 2
  for (int k4 = 0; k4 < 32; ++k4) {
    float w0 = wp[(size_t)(k4 * 4 + 0) * NCH];
    float w1 = wp[(size_t)(k4 * 4 + 1) * NCH];
    float w2 = wp[(size_t)(k4 * 4 + 2) * NCH];
    float w3 = wp[(size_t)(k4 * 4 + 3) * NCH];
    #pragma unroll
    for (int bi = 0; bi < 16; ++bi) {
      float4 u = us[bi][k4];                       // LDS broadcast
      acc[bi] += u.x * w0 + u.y * w1 + u.z * w2 + u.w * w3;
    }
  }
  const size_t base = (size_t)blockIdx.y * XG_N + c * HDIM + h;
  #pragma unroll
  for (int bi = 0; bi < 16; ++bi)
    wsh_part[base + (size_t)(b0 + bi) * NCH] = acc[bi];
}

// ---------------------------------------------------------------------------
// kH: ws = sum8 wsh_part + bl; hid = relu(ws@Wh+bh); bbox/presence heads.
// grid (32 b, 12 cg3) x 256 (thread = j).
__global__ __launch_bounds__(256) void kH_heads(
    const float* __restrict__ Wh, const float* __restrict__ bh,
    const float* __restrict__ Wr, const float* __restrict__ br,
    const float* __restrict__ Wc, const float* __restrict__ bc,
    const float* __restrict__ bl,
    const float* __restrict__ wsh_part, float* __restrict__ out) {
  __shared__ float ws_s[3][HDIM];
  __shared__ float hid_s[3][HDIM];
  const int b = blockIdx.x, c0 = blockIdx.y * 3;
  const int j = threadIdx.x;

  #pragma unroll
  for (int ci = 0; ci < 3; ++ci) {
    size_t base = (size_t)b * NCH + (c0 + ci) * HDIM + j;
    float s = bl[(c0 + ci) * HDIM + j];
    #pragma unroll
    for (int p = 0; p < 8; ++p) s += wsh_part[(size_t)p * XG_N + base];
    ws_s[ci][j] = s;
  }
  __syncthreads();

  float acc[3] = {0,0,0};
  for (int h = 0; h < HDIM; ++h) {
    float whj = Wh[(size_t)h * HDIM + j];
    acc[0] += ws_s[0][h] * whj;
    acc[1] += ws_s[1][h] * whj;
    acc[2] += ws_s[2][h] * whj;
  }
  float bj = bh[j];
  #pragma unroll
  for (int ci = 0; ci < 3; ++ci) hid_s[ci][j] = fmaxf(acc[ci] + bj, 0.0f);
  __syncthreads();

  const int r = j >> 6, j0 = j & 63;
  for (int ci = 0; ci < 3; ++ci) {
    const int c = c0 + ci;
    float s = 0.f;
    #pragma unroll
    for (int m = 0; m < 4; ++m)
      s += hid_s[ci][j0 + 64 * m] * Wr[(j0 + 64 * m) * 4 + r];
    #pragma unroll
    for (int off = 32; off >= 1; off >>= 1) s += __shfl_xor(s, off);
    if (j0 == 0) out[(size_t)b * (NCLS * 4) + c * 4 + r] = s + br[r];
    if (r == 0) {
      float p = 0.f;
      #pragma unroll
      for (int m = 0; m < 4; ++m)
        p += hid_s[ci][j0 + 64 * m] * Wc[j0 + 64 * m];
      #pragma unroll
      for (int off = 32; off >= 1; off >>= 1) p += __shfl_xor(p, off);
      if (j0 == 0) out[BSZ * NCLS * 4 + b * NCLS + c] = p + bc[0];
    }
  }
}

// ---------------------------------------------------------------------------
extern "C" void kernel_launch(void* const* d_in, const int* in_sizes, int n_in,
                              void* d_out, int out_size, void* d_ws, size_t ws_size,
                              hipStream_t stream) {
  const float* local = (const float*)d_in[0];
  const float* gap   = (const float*)d_in[1];
  const float* Wl    = (const float*)d_in[2];
  const float* bl    = (const float*)d_in[3];
  const float* Wg    = (const float*)d_in[4];
  const float* bg    = (const float*)d_in[5];
  const float* Wh    = (const float*)d_in[6];
  const float* bh    = (const float*)d_in[7];
  const float* Wr    = (const float*)d_in[8];
  const float* br    = (const float*)d_in[9];
  const float* Wc    = (const float*)d_in[10];
  const float* bc    = (const float*)d_in[11];
  float* out         = (float*)d_out;

  // A: 8*XG_N floats — xg_part, then sc_part (8*SC_N fits), then wsh_part
  // B: XG_N — xg;  C: V_N — V;  D: SC_N — attn2;  E: V_N — U
  float* A  = (float*)d_ws;
  float* B  = A + (size_t)8 * XG_N;
  float* C  = B + XG_N;
  float* D  = C + V_N;
  float* E  = D + SC_N;

  kB_xg_part<<<dim3(36, 8, 2), dim3(256), 0, stream>>>(Wg, gap, A);
  kBr_xg   <<<dim3(XG_N / 256), dim3(256), 0, stream>>>(A, bg, B);
  kC_V     <<<dim3(36, 4, 4), dim3(256), 0, stream>>>(Wl, B, C);
  kD_scores<<<dim3(32, 3, 8), dim3(256), 0, stream>>>(local, C, A);
  kE_softmax<<<dim3(32, 36), dim3(64), 0, stream>>>(A, D);
  kF_U     <<<dim3(32, 8, 3), dim3(256), 0, stream>>>(local, D, E);
  kG_ws    <<<dim3(36, 8, 2), dim3(256), 0, stream>>>(Wl, E, A);
  kH_heads <<<dim3(32, 12), dim3(256), 0, stream>>>(Wh, bh, Wr, br, Wc, bc, bl, A, out);
}